// Round 1
// baseline (2049.909 us; speedup 1.0000x reference)
//
#include <hip/hip_runtime.h>

#define DEVINL __device__ __forceinline__

typedef unsigned short u16;
typedef __attribute__((ext_vector_type(8))) short bf16x8;   // 8 bf16 = 4 VGPRs (MFMA A/B frag)
typedef __attribute__((ext_vector_type(4))) float f32x4;     // MFMA C/D frag
typedef __attribute__((ext_vector_type(4))) unsigned short u16x4;

// B=4, S=1024, HID=4096, NH=32, NKV=8, HD=128, FF=11008

DEVINL float bf2f(u16 u) { union { unsigned i; float f; } x; x.i = ((unsigned)u) << 16; return x.f; }
DEVINL u16 f2bf(float f) {                       // round-to-nearest-even
  union { float f; unsigned i; } x; x.f = f;
  unsigned r = x.i + 0x7fffu + ((x.i >> 16) & 1u);
  return (u16)(r >> 16);
}

// async global->LDS, 16B per lane; lds base must be wave-uniform (HW: base + lane*16)
DEVINL void async16(u16* lds, const u16* g) {
  __builtin_amdgcn_global_load_lds((const __attribute__((address_space(1))) unsigned*)g,
                                   (__attribute__((address_space(3))) unsigned*)lds, 16, 0, 0);
}

// ---------------- weight convert + transpose: in fp32 [K,N] -> out bf16 [N,K] ----------------
__global__ __launch_bounds__(256) void conv_t(const float* __restrict__ in,
                                              u16* __restrict__ out, int K, int N) {
  __shared__ float tile[64][65];
  int k0 = blockIdx.y << 6, n0 = blockIdx.x << 6;
  int t = threadIdx.x;
  int r = t >> 4, c4 = (t & 15) << 2;
  #pragma unroll
  for (int it = 0; it < 4; it++) {
    int row = r + it*16;
    f32x4 v = *(const f32x4*)(in + (size_t)(k0 + row)*N + n0 + c4);
    tile[row][c4+0] = v[0]; tile[row][c4+1] = v[1];
    tile[row][c4+2] = v[2]; tile[row][c4+3] = v[3];
  }
  __syncthreads();
  #pragma unroll
  for (int it = 0; it < 4; it++) {
    int nrow = r + it*16;
    u16x4 ov;
    #pragma unroll
    for (int e = 0; e < 4; e++) ov[e] = f2bf(tile[c4+e][nrow]);
    *(u16x4*)(out + (size_t)(n0 + nrow)*K + k0 + c4) = ov;
  }
}

// ---------------- RMSNorm: fp32 in [4096 rows x 4096] -> bf16 out ----------------
__global__ __launch_bounds__(256) void rmsnorm_kernel(const float* __restrict__ x,
                                                      const float* __restrict__ w,
                                                      u16* __restrict__ out) {
  int row = blockIdx.x, t = threadIdx.x;
  const float* xr = x + (size_t)row * 4096;
  f32x4 v[4];
  float ss = 0.f;
  #pragma unroll
  for (int i = 0; i < 4; i++) {
    v[i] = *(const f32x4*)(xr + (t + 256*i)*4);
    ss += v[i][0]*v[i][0] + v[i][1]*v[i][1] + v[i][2]*v[i][2] + v[i][3]*v[i][3];
  }
  #pragma unroll
  for (int d = 1; d < 64; d <<= 1) ss += __shfl_xor(ss, d, 64);
  __shared__ float ps[4];
  if ((t & 63) == 0) ps[t >> 6] = ss;
  __syncthreads();
  float scale = rsqrtf((ps[0]+ps[1]+ps[2]+ps[3]) * (1.f/4096.f) + 1e-6f);
  #pragma unroll
  for (int i = 0; i < 4; i++) {
    f32x4 wv = *(const f32x4*)(w + (t + 256*i)*4);
    u16x4 o;
    #pragma unroll
    for (int e = 0; e < 4; e++) o[e] = f2bf(v[i][e] * scale * wv[e]);
    *(u16x4*)(out + (size_t)row*4096 + (t + 256*i)*4) = o;
  }
}

// ---------------- RoPE in-place on q [tok,32*128] & k [tok,8*128]; q gets 1/sqrt(HD) ----------------
__global__ __launch_bounds__(256) void rope_kernel(u16* __restrict__ q, u16* __restrict__ k) {
  int tok = blockIdx.x;            // b*1024 + s ; position id == s
  int s = tok & 1023;
  __shared__ float cs[64], sn[64];
  int t = threadIdx.x;
  if (t < 64) {
    float inv = __expf(-(float)t * 0.14391156934f);  // ln(10000)/64
    float ang = (float)s * inv;
    cs[t] = cosf(ang); sn[t] = sinf(ang);
  }
  __syncthreads();
  const float qscale = 0.08838834764831845f;          // 1/sqrt(128)
  size_t qbase = (size_t)tok * 4096;
  #pragma unroll
  for (int it = 0; it < 8; it++) {
    int item = t + it*256; int h = item >> 6, j = item & 63;
    size_t i0 = qbase + h*128 + j;
    float x1 = bf2f(q[i0]), x2 = bf2f(q[i0+64]);
    float c = cs[j], si = sn[j];
    q[i0]    = f2bf((x1*c - x2*si) * qscale);
    q[i0+64] = f2bf((x2*c + x1*si) * qscale);
  }
  size_t kbase = (size_t)tok * 1024;
  #pragma unroll
  for (int it = 0; it < 2; it++) {
    int item = t + it*256; int h = item >> 6, j = item & 63;
    size_t i0 = kbase + h*128 + j;
    float x1 = bf2f(k[i0]), x2 = bf2f(k[i0+64]);
    float c = cs[j], si = sn[j];
    k[i0]    = f2bf(x1*c - x2*si);
    k[i0+64] = f2bf(x2*c + x1*si);
  }
}

// ---------------- V transpose per (b,kvh): [1024 x 128] -> vt [128 x 1024] ----------------
__global__ __launch_bounds__(256) void vtrans(const u16* __restrict__ v, u16* __restrict__ vt) {
  __shared__ u16 tile[32][33];
  int bh = blockIdx.z; int b = bh >> 3, kvh = bh & 7;
  int d0 = blockIdx.x << 5, s0 = blockIdx.y << 5;
  int tx = threadIdx.x, ty = threadIdx.y;   // (32,8)
  for (int r = ty; r < 32; r += 8)
    tile[r][tx] = v[(size_t)(b*1024 + s0 + r)*1024 + kvh*128 + d0 + tx];
  __syncthreads();
  for (int r = ty; r < 32; r += 8)
    vt[(size_t)((b*8 + kvh)*128 + d0 + r)*1024 + s0 + tx] = tile[tx][r];
}

// ---------------- GEMM: C[M,N] = A[M,K](bf16) * Bt[N,K](bf16)^T ----------------
// 128x128 tile, BK=64, 4 waves (2x2, 64x64 each), mfma 16x16x32 bf16.
// Staging: global_load_lds 16B, LDS rows 128B with T2 XOR-swizzle applied on the
// pre-swizzled GLOBAL source (rule #21); ds_read_b128 applies same swizzle.
// EPI: 0 = bf16 out; 1 = fp32 out + resid; 2 = bf16 out = silu(gate)*acc
template<int EPI>
__global__ __launch_bounds__(256, 2) void gemm_bt(
    const u16* __restrict__ A, const u16* __restrict__ Bt,
    void* __restrict__ Cv, const float* __restrict__ resid,
    const u16* __restrict__ gate, int M, int N, int K) {
  __shared__ u16 As[128*64];
  __shared__ u16 Bs[128*64];
  int nwg = gridDim.x;
  int bid = (int)blockIdx.x;
  int cpx = nwg >> 3;                       // nwg % 8 == 0 for all our shapes
  int swz = (bid & 7) * cpx + (bid >> 3);   // XCD-contiguous chunks (T1)
  int mt = M >> 7;
  int m0 = (swz % mt) << 7;                 // panel-major: consecutive swz share n-panel
  int n0 = (swz / mt) << 7;
  int tid = threadIdx.x;
  int lane = tid & 63, wave = tid >> 6;
  int wm = wave >> 1, wn = wave & 1;

  f32x4 acc[4][4];
  f32x4 zero = {0.f, 0.f, 0.f, 0.f};
  #pragma unroll
  for (int i = 0; i < 4; i++)
    #pragma unroll
    for (int j = 0; j < 4; j++) acc[i][j] = zero;

  int arow[4], acolb[4];
  #pragma unroll
  for (int i = 0; i < 4; i++) {
    int c = i*256 + tid;                    // 16B chunk id; row = 128B = 8 chunks
    arow[i]  = c >> 3;
    acolb[i] = ((c & 7) * 16) ^ ((arow[i] & 7) << 4);   // pre-swizzled source byte-col
  }

  int nsteps = K >> 6;
  for (int t = 0; t < nsteps; t++) {
    int k0 = t << 6;
    #pragma unroll
    for (int i = 0; i < 4; i++) {
      async16(As + i*2048 + wave*512, A  + (size_t)(m0 + arow[i])*K + k0 + (acolb[i] >> 1));
      async16(Bs + i*2048 + wave*512, Bt + (size_t)(n0 + arow[i])*K + k0 + (acolb[i] >> 1));
    }
    __syncthreads();
    #pragma unroll
    for (int ks = 0; ks < 2; ks++) {
      bf16x8 af[4], bfr[4];
      int c2 = (ks*32 + (lane >> 4)*8) * 2;
      #pragma unroll
      for (int mf = 0; mf < 4; mf++) {
        int r = wm*64 + mf*16 + (lane & 15);
        af[mf] = *(const bf16x8*)(As + r*64 + ((c2 ^ ((r & 7) << 4)) >> 1));
      }
      #pragma unroll
      for (int nf = 0; nf < 4; nf++) {
        int r = wn*64 + nf*16 + (lane & 15);
        bfr[nf] = *(const bf16x8*)(Bs + r*64 + ((c2 ^ ((r & 7) << 4)) >> 1));
      }
      #pragma unroll
      for (int mf = 0; mf < 4; mf++)
        #pragma unroll
        for (int nf = 0; nf < 4; nf++)
          acc[mf][nf] = __builtin_amdgcn_mfma_f32_16x16x32_bf16(af[mf], bfr[nf], acc[mf][nf], 0, 0, 0);
    }
    __syncthreads();
  }

  // C/D layout: col = lane&15, row = (lane>>4)*4 + j  [m89/m91]
  #pragma unroll
  for (int mf = 0; mf < 4; mf++)
    #pragma unroll
    for (int nf = 0; nf < 4; nf++)
      #pragma unroll
      for (int j = 0; j < 4; j++) {
        int rr = m0 + wm*64 + mf*16 + (lane >> 4)*4 + j;
        int cc = n0 + wn*64 + nf*16 + (lane & 15);
        size_t idx = (size_t)rr * N + cc;
        float v = acc[mf][nf][j];
        if constexpr (EPI == 0) {
          ((u16*)Cv)[idx] = f2bf(v);
        } else if constexpr (EPI == 1) {
          ((float*)Cv)[idx] = v + resid[idx];
        } else {
          float g = bf2f(gate[idx]);
          float sg = g / (1.f + __expf(-g));
          ((u16*)Cv)[idx] = f2bf(sg * v);
        }
      }
}

// ---------------- Flash attention, causal, GQA 4:1 ----------------
// grid: b(4) * h(32) * qtile(16); block 256 = 4 waves, each wave 16 q-rows.
// q pre-scaled by 1/sqrt(HD). K staged [64][128] swizzled; V pre-transposed -> Vs [128][64] swizzled.
__global__ __launch_bounds__(256, 2) void attn_kernel(
    const u16* __restrict__ q, const u16* __restrict__ k,
    const u16* __restrict__ vt, u16* __restrict__ out) {
  __shared__ u16 Ks[64*128];
  __shared__ u16 Vs[128*64];
  __shared__ u16 Ps[4*16*64];               // per-wave P tile
  int bid = blockIdx.x;
  int qt = bid & 15;
  int h  = (bid >> 4) & 31;
  int b  = bid >> 9;
  int kvh = h >> 2;
  int tid = threadIdx.x, lane = tid & 63, wave = tid >> 6;
  int q0 = qt << 6;

  bf16x8 qf[4];
  {
    const u16* qb_ = q + (size_t)(b*1024 + q0 + wave*16 + (lane & 15))*4096 + h*128 + (lane >> 4)*8;
    #pragma unroll
    for (int ks = 0; ks < 4; ks++) qf[ks] = *(const bf16x8*)(qb_ + ks*32);
  }
  f32x4 o[8];
  f32x4 zero = {0.f,0.f,0.f,0.f};
  #pragma unroll
  for (int i = 0; i < 8; i++) o[i] = zero;
  float m[4] = {-1e30f,-1e30f,-1e30f,-1e30f};
  float l[4] = {0.f,0.f,0.f,0.f};

  int kr[4], kc[4], vr[4], vc[4];
  #pragma unroll
  for (int i = 0; i < 4; i++) {
    int c = i*256 + tid;
    kr[i] = c >> 4; kc[i] = ((c & 15)*16) ^ ((kr[i] & 7) << 4);   // K rows = 256B = 16 chunks
    vr[i] = c >> 3; vc[i] = ((c & 7)*16)  ^ ((vr[i] & 7) << 4);   // Vs rows = 128B = 8 chunks
  }

  for (int t = 0; t <= qt; t++) {
    int kv0 = t << 6;
    #pragma unroll
    for (int i = 0; i < 4; i++) {
      async16(Ks + i*2048 + wave*512, k  + (size_t)(b*1024 + kv0 + kr[i])*1024 + kvh*128 + (kc[i] >> 1));
      async16(Vs + i*2048 + wave*512, vt + (size_t)((b*8 + kvh)*128 + vr[i])*1024 + kv0 + (vc[i] >> 1));
    }
    __syncthreads();

    f32x4 s[4];
    #pragma unroll
    for (int nf = 0; nf < 4; nf++) {
      s[nf] = zero;
      #pragma unroll
      for (int ks = 0; ks < 4; ks++) {
        int r = nf*16 + (lane & 15);
        int c2 = (ks*32 + (lane >> 4)*8)*2;
        bf16x8 kf = *(const bf16x8*)(Ks + r*128 + ((c2 ^ ((r & 7) << 4)) >> 1));
        s[nf] = __builtin_amdgcn_mfma_f32_16x16x32_bf16(qf[ks], kf, s[nf], 0, 0, 0);
      }
    }
    if (t == qt) {                          // diagonal tile: kv0 == q0
      #pragma unroll
      for (int nf = 0; nf < 4; nf++)
        #pragma unroll
        for (int j = 0; j < 4; j++) {
          int cc = nf*16 + (lane & 15);
          int rr = wave*16 + (lane >> 4)*4 + j;
          if (cc > rr) s[nf][j] = -1e30f;
        }
    }
    // online softmax; row-groups: lane>>4 fixed => shuffle over lane&15 only
    #pragma unroll
    for (int j = 0; j < 4; j++) {
      float mx = fmaxf(fmaxf(s[0][j], s[1][j]), fmaxf(s[2][j], s[3][j]));
      #pragma unroll
      for (int d = 1; d < 16; d <<= 1) mx = fmaxf(mx, __shfl_xor(mx, d, 64));
      float mn = fmaxf(m[j], mx);
      float f = __expf(m[j] - mn);
      m[j] = mn;
      float ssum = 0.f;
      #pragma unroll
      for (int nf = 0; nf < 4; nf++) {
        float p = __expf(s[nf][j] - mn);
        s[nf][j] = p; ssum += p;
      }
      #pragma unroll
      for (int d = 1; d < 16; d <<= 1) ssum += __shfl_xor(ssum, d, 64);
      l[j] = l[j]*f + ssum;
      #pragma unroll
      for (int nf = 0; nf < 8; nf++) o[nf][j] *= f;
    }
    // P -> per-wave LDS (bf16, swizzled) to re-layout C-frag -> A-frag
    #pragma unroll
    for (int nf = 0; nf < 4; nf++)
      #pragma unroll
      for (int j = 0; j < 4; j++) {
        int rr = (lane >> 4)*4 + j;
        int cb = ((nf*16 + (lane & 15))*2) ^ ((rr & 7) << 4);
        Ps[wave*1024 + rr*64 + (cb >> 1)] = f2bf(s[nf][j]);
      }
    #pragma unroll
    for (int ks2 = 0; ks2 < 2; ks2++) {
      int mr = lane & 15;
      int c2 = (ks2*32 + (lane >> 4)*8)*2;
      bf16x8 pa = *(const bf16x8*)(Ps + wave*1024 + mr*64 + ((c2 ^ ((mr & 7) << 4)) >> 1));
      #pragma unroll
      for (int nf = 0; nf < 8; nf++) {
        int d = nf*16 + (lane & 15);
        bf16x8 vf = *(const bf16x8*)(Vs + d*64 + ((c2 ^ ((d & 7) << 4)) >> 1));
        o[nf] = __builtin_amdgcn_mfma_f32_16x16x32_bf16(pa, vf, o[nf], 0, 0, 0);
      }
    }
    __syncthreads();
  }

  float inv[4];
  #pragma unroll
  for (int j = 0; j < 4; j++) inv[j] = 1.f / l[j];
  u16* ob = out + (size_t)(b*1024 + q0 + wave*16)*4096 + h*128;
  #pragma unroll
  for (int nf = 0; nf < 8; nf++)
    #pragma unroll
    for (int j = 0; j < 4; j++) {
      int rr = (lane >> 4)*4 + j;
      int cc = nf*16 + (lane & 15);
      ob[(size_t)rr*4096 + cc] = f2bf(o[nf][j] * inv[j]);
    }
}

// ---------------- driver ----------------
extern "C" void kernel_launch(void* const* d_in, const int* in_sizes, int n_in,
                              void* d_out, int out_size, void* d_ws, size_t ws_size,
                              hipStream_t stream) {
  (void)in_sizes; (void)n_in; (void)out_size;
  const float* hidden = (const float*)d_in[0];
  const float* Wq  = (const float*)d_in[3];
  const float* Wk  = (const float*)d_in[4];
  const float* Wv  = (const float*)d_in[5];
  const float* Wo  = (const float*)d_in[6];
  const float* ln1 = (const float*)d_in[7];
  const float* ln2 = (const float*)d_in[8];
  const float* Wg  = (const float*)d_in[9];
  const float* Wu  = (const float*)d_in[10];
  const float* Wd  = (const float*)d_in[11];
  float* out = (float*)d_out;

  char* ws = (char*)d_ws;
  size_t off = 0;
  auto alloc = [&](size_t b) { char* p = ws + off; off += (b + 4095) & ~(size_t)4095; return p; };
  u16*  W1   = (u16*)alloc(90177536);    // one bf16-transposed weight at a time (max = FF weights)
  u16*  h1   = (u16*)alloc(33554432);    // norm1 out; later reused as attention out
  u16*  qb   = (u16*)alloc(33554432);    // q; later reused as h2 (norm2 out)
  u16*  kb   = (u16*)alloc(8388608);
  u16*  vb   = (u16*)alloc(8388608);
  u16*  vtb  = (u16*)alloc(8388608);
  float* hmid = (float*)alloc(67108864); // residual after attention (fp32)
  u16*  gb   = (u16*)alloc(90177536);    // gate; reused as act = silu(g)*u
  if (off > ws_size) return;             // ws too small -> fail visibly

  u16* wqT = W1;                  // [4096,4096]
  u16* wkT = W1 + 16777216;       // [1024,4096]
  u16* wvT = wkT + 4194304;       // [1024,4096]

  dim3 blk(256);
  // 1) QKV weights -> bf16 transposed
  conv_t<<<dim3(64, 64),  blk, 0, stream>>>(Wq, wqT, 4096, 4096);
  conv_t<<<dim3(16, 64),  blk, 0, stream>>>(Wk, wkT, 4096, 1024);
  conv_t<<<dim3(16, 64),  blk, 0, stream>>>(Wv, wvT, 4096, 1024);
  // 2) norm1
  rmsnorm_kernel<<<4096, blk, 0, stream>>>(hidden, ln1, h1);
  // 3) QKV projections
  gemm_bt<0><<<1024, blk, 0, stream>>>(h1, wqT, qb, nullptr, nullptr, 4096, 4096, 4096);
  gemm_bt<0><<<256,  blk, 0, stream>>>(h1, wkT, kb, nullptr, nullptr, 4096, 1024, 4096);
  gemm_bt<0><<<256,  blk, 0, stream>>>(h1, wvT, vb, nullptr, nullptr, 4096, 1024, 4096);
  // 4) RoPE (q also gets 1/sqrt(HD))
  rope_kernel<<<4096, blk, 0, stream>>>(qb, kb);
  // 5) V transpose for PV fragment reads
  vtrans<<<dim3(4, 32, 32), dim3(32, 8), 0, stream>>>(vb, vtb);
  // 6) attention -> h1 (free after QKV)
  attn_kernel<<<2048, blk, 0, stream>>>(qb, kb, vtb, h1);
  // 7) Wo + residual -> hmid (fp32)
  conv_t<<<dim3(64, 64), blk, 0, stream>>>(Wo, W1, 4096, 4096);
  gemm_bt<1><<<1024, blk, 0, stream>>>(h1, W1, hmid, hidden, nullptr, 4096, 4096, 4096);
  // 8) norm2 -> qb (q free after attention)
  rmsnorm_kernel<<<4096, blk, 0, stream>>>(hmid, ln2, qb);
  // 9) gate
  conv_t<<<dim3(172, 64), blk, 0, stream>>>(Wg, W1, 4096, 11008);
  gemm_bt<0><<<2752, blk, 0, stream>>>(qb, W1, gb, nullptr, nullptr, 4096, 11008, 4096);
  // 10) up, epilogue act = silu(gate)*up (in place over gb)
  conv_t<<<dim3(172, 64), blk, 0, stream>>>(Wu, W1, 4096, 11008);
  gemm_bt<2><<<2752, blk, 0, stream>>>(qb, W1, gb, nullptr, gb, 4096, 11008, 4096);
  // 11) down + residual -> d_out (fp32)
  conv_t<<<dim3(64, 172), blk, 0, stream>>>(Wd, W1, 11008, 4096);
  gemm_bt<1><<<1024, blk, 0, stream>>>(gb, W1, out, hmid, nullptr, 4096, 4096, 11008);
}

// Round 2
// 1864.431 us; speedup vs baseline: 1.0995x; 1.0995x over previous
//
#include <hip/hip_runtime.h>

#define DEVINL __device__ __forceinline__

typedef unsigned short u16;
typedef __attribute__((ext_vector_type(8))) short bf16x8;   // 8 bf16 = 4 VGPRs (MFMA A/B frag)
typedef __attribute__((ext_vector_type(4))) float f32x4;     // MFMA C/D frag
typedef __attribute__((ext_vector_type(4))) unsigned short u16x4;

// B=4, S=1024, HID=4096, NH=32, NKV=8, HD=128, FF=11008

DEVINL float bf2f(u16 u) { union { unsigned i; float f; } x; x.i = ((unsigned)u) << 16; return x.f; }
DEVINL u16 f2bf(float f) {                       // round-to-nearest-even
  union { float f; unsigned i; } x; x.f = f;
  unsigned r = x.i + 0x7fffu + ((x.i >> 16) & 1u);
  return (u16)(r >> 16);
}

// async global->LDS, 16B per lane; lds base must be wave-uniform (HW: base + lane*16)
DEVINL void async16(u16* lds, const u16* g) {
  __builtin_amdgcn_global_load_lds((const __attribute__((address_space(1))) unsigned*)g,
                                   (__attribute__((address_space(3))) unsigned*)lds, 16, 0, 0);
}

// ---------------- weight convert + transpose: in fp32 [K,N] -> out bf16 [N,K] ----------------
__global__ __launch_bounds__(256) void conv_t(const float* __restrict__ in,
                                              u16* __restrict__ out, int K, int N) {
  __shared__ float tile[64][65];
  int k0 = blockIdx.y << 6, n0 = blockIdx.x << 6;
  int t = threadIdx.x;
  int r = t >> 4, c4 = (t & 15) << 2;
  #pragma unroll
  for (int it = 0; it < 4; it++) {
    int row = r + it*16;
    f32x4 v = *(const f32x4*)(in + (size_t)(k0 + row)*N + n0 + c4);
    tile[row][c4+0] = v[0]; tile[row][c4+1] = v[1];
    tile[row][c4+2] = v[2]; tile[row][c4+3] = v[3];
  }
  __syncthreads();
  #pragma unroll
  for (int it = 0; it < 4; it++) {
    int nrow = r + it*16;
    u16x4 ov;
    #pragma unroll
    for (int e = 0; e < 4; e++) ov[e] = f2bf(tile[c4+e][nrow]);
    *(u16x4*)(out + (size_t)(n0 + nrow)*K + k0 + c4) = ov;
  }
}

// ---------------- RMSNorm: fp32 in [4096 rows x 4096] -> bf16 out ----------------
__global__ __launch_bounds__(256) void rmsnorm_kernel(const float* __restrict__ x,
                                                      const float* __restrict__ w,
                                                      u16* __restrict__ out) {
  int row = blockIdx.x, t = threadIdx.x;
  const float* xr = x + (size_t)row * 4096;
  f32x4 v[4];
  float ss = 0.f;
  #pragma unroll
  for (int i = 0; i < 4; i++) {
    v[i] = *(const f32x4*)(xr + (t + 256*i)*4);
    ss += v[i][0]*v[i][0] + v[i][1]*v[i][1] + v[i][2]*v[i][2] + v[i][3]*v[i][3];
  }
  #pragma unroll
  for (int d = 1; d < 64; d <<= 1) ss += __shfl_xor(ss, d, 64);
  __shared__ float ps[4];
  if ((t & 63) == 0) ps[t >> 6] = ss;
  __syncthreads();
  float scale = rsqrtf((ps[0]+ps[1]+ps[2]+ps[3]) * (1.f/4096.f) + 1e-6f);
  #pragma unroll
  for (int i = 0; i < 4; i++) {
    f32x4 wv = *(const f32x4*)(w + (t + 256*i)*4);
    u16x4 o;
    #pragma unroll
    for (int e = 0; e < 4; e++) o[e] = f2bf(v[i][e] * scale * wv[e]);
    *(u16x4*)(out + (size_t)row*4096 + (t + 256*i)*4) = o;
  }
}

// ---------------- RoPE in-place on q [tok,32*128] & k [tok,8*128]; q gets 1/sqrt(HD) ----------------
__global__ __launch_bounds__(256) void rope_kernel(u16* __restrict__ q, u16* __restrict__ k) {
  int tok = blockIdx.x;            // b*1024 + s ; position id == s
  int s = tok & 1023;
  __shared__ float cs[64], sn[64];
  int t = threadIdx.x;
  if (t < 64) {
    float inv = __expf(-(float)t * 0.14391156934f);  // ln(10000)/64
    float ang = (float)s * inv;
    cs[t] = cosf(ang); sn[t] = sinf(ang);
  }
  __syncthreads();
  const float qscale = 0.08838834764831845f;          // 1/sqrt(128)
  size_t qbase = (size_t)tok * 4096;
  #pragma unroll
  for (int it = 0; it < 8; it++) {
    int item = t + it*256; int h = item >> 6, j = item & 63;
    size_t i0 = qbase + h*128 + j;
    float x1 = bf2f(q[i0]), x2 = bf2f(q[i0+64]);
    float c = cs[j], si = sn[j];
    q[i0]    = f2bf((x1*c - x2*si) * qscale);
    q[i0+64] = f2bf((x2*c + x1*si) * qscale);
  }
  size_t kbase = (size_t)tok * 1024;
  #pragma unroll
  for (int it = 0; it < 2; it++) {
    int item = t + it*256; int h = item >> 6, j = item & 63;
    size_t i0 = kbase + h*128 + j;
    float x1 = bf2f(k[i0]), x2 = bf2f(k[i0+64]);
    float c = cs[j], si = sn[j];
    k[i0]    = f2bf(x1*c - x2*si);
    k[i0+64] = f2bf(x2*c + x1*si);
  }
}

// ---------------- V transpose per (b,kvh): [1024 x 128] -> vt [128 x 1024] ----------------
__global__ __launch_bounds__(256) void vtrans(const u16* __restrict__ v, u16* __restrict__ vt) {
  __shared__ u16 tile[32][33];
  int bh = blockIdx.z; int b = bh >> 3, kvh = bh & 7;
  int d0 = blockIdx.x << 5, s0 = blockIdx.y << 5;
  int tx = threadIdx.x, ty = threadIdx.y;   // (32,8)
  for (int r = ty; r < 32; r += 8)
    tile[r][tx] = v[(size_t)(b*1024 + s0 + r)*1024 + kvh*128 + d0 + tx];
  __syncthreads();
  for (int r = ty; r < 32; r += 8)
    vt[(size_t)((b*8 + kvh)*128 + d0 + r)*1024 + s0 + tx] = tile[tx][r];
}

// ---------------- 128-tile GEMM (kept for K/V projections: N=1024 too small for 256-tiles) ----------------
template<int EPI>
__global__ __launch_bounds__(256, 2) void gemm_bt(
    const u16* __restrict__ A, const u16* __restrict__ Bt,
    void* __restrict__ Cv, const float* __restrict__ resid,
    const u16* __restrict__ gate, int M, int N, int K) {
  __shared__ u16 As[128*64];
  __shared__ u16 Bs[128*64];
  int nwg = gridDim.x;
  int bid = (int)blockIdx.x;
  int cpx = nwg >> 3;
  int swz = (bid & 7) * cpx + (bid >> 3);
  int mt = M >> 7;
  int m0 = (swz % mt) << 7;
  int n0 = (swz / mt) << 7;
  int tid = threadIdx.x;
  int lane = tid & 63, wave = tid >> 6;
  int wm = wave >> 1, wn = wave & 1;

  f32x4 acc[4][4];
  f32x4 zero = {0.f, 0.f, 0.f, 0.f};
  #pragma unroll
  for (int i = 0; i < 4; i++)
    #pragma unroll
    for (int j = 0; j < 4; j++) acc[i][j] = zero;

  int arow[4], acolb[4];
  #pragma unroll
  for (int i = 0; i < 4; i++) {
    int c = i*256 + tid;
    arow[i]  = c >> 3;
    acolb[i] = ((c & 7) * 16) ^ ((arow[i] & 7) << 4);
  }

  int nsteps = K >> 6;
  for (int t = 0; t < nsteps; t++) {
    int k0 = t << 6;
    #pragma unroll
    for (int i = 0; i < 4; i++) {
      async16(As + i*2048 + wave*512, A  + (size_t)(m0 + arow[i])*K + k0 + (acolb[i] >> 1));
      async16(Bs + i*2048 + wave*512, Bt + (size_t)(n0 + arow[i])*K + k0 + (acolb[i] >> 1));
    }
    __syncthreads();
    #pragma unroll
    for (int ks = 0; ks < 2; ks++) {
      bf16x8 af[4], bfr[4];
      int c2 = (ks*32 + (lane >> 4)*8) * 2;
      #pragma unroll
      for (int mf = 0; mf < 4; mf++) {
        int r = wm*64 + mf*16 + (lane & 15);
        af[mf] = *(const bf16x8*)(As + r*64 + ((c2 ^ ((r & 7) << 4)) >> 1));
      }
      #pragma unroll
      for (int nf = 0; nf < 4; nf++) {
        int r = wn*64 + nf*16 + (lane & 15);
        bfr[nf] = *(const bf16x8*)(Bs + r*64 + ((c2 ^ ((r & 7) << 4)) >> 1));
      }
      #pragma unroll
      for (int mf = 0; mf < 4; mf++)
        #pragma unroll
        for (int nf = 0; nf < 4; nf++)
          acc[mf][nf] = __builtin_amdgcn_mfma_f32_16x16x32_bf16(af[mf], bfr[nf], acc[mf][nf], 0, 0, 0);
    }
    __syncthreads();
  }

  #pragma unroll
  for (int mf = 0; mf < 4; mf++)
    #pragma unroll
    for (int nf = 0; nf < 4; nf++)
      #pragma unroll
      for (int j = 0; j < 4; j++) {
        int rr = m0 + wm*64 + mf*16 + (lane >> 4)*4 + j;
        int cc = n0 + wn*64 + nf*16 + (lane & 15);
        size_t idx = (size_t)rr * N + cc;
        float v = acc[mf][nf][j];
        if constexpr (EPI == 0) {
          ((u16*)Cv)[idx] = f2bf(v);
        } else if constexpr (EPI == 1) {
          ((float*)Cv)[idx] = v + resid[idx];
        } else {
          float g = bf2f(gate[idx]);
          float sg = g / (1.f + __expf(-g));
          ((u16*)Cv)[idx] = f2bf(sg * v);
        }
      }
}

// ---------------- 256x256 8-phase GEMM (T2+T3+T4+T5): C[M,N] = A[M,K] * Bt[N,K]^T ----------------
// 512 thr = 8 waves (2M x 4N), each wave 128x64 out. BK=64, LDS 128 KiB = 2buf x (A 32KB + B 32KB).
// Phases per K-tile (quadrant qm,qn): ph0: ldA(qm0,8)+ldB(qn0,4); ph1: ldB(qn1,4);
// ph2: ldA(qm1,8)+stage B(k+2); ph3: stage A(k+2). Counted vmcnt(8) once per K-tile (phase-4 end).
// Safety: B halves of buf[k&1] fully consumed end-ph1, A halves end-ph2 (readers drain via
// lgkmcnt(0) before their MFMA; end-barrier orders cross-wave). vmcnt(8)+end-barrier at ph3 makes
// K-tile k+1 (staged 2 tiles ago, older than the 8 newest loads) visible to all waves.
#define MIDBAR() do { __builtin_amdgcn_sched_barrier(0); __builtin_amdgcn_s_barrier(); \
  asm volatile("s_waitcnt lgkmcnt(0)" ::: "memory"); __builtin_amdgcn_sched_barrier(0); } while (0)
#define ENDBAR() do { __builtin_amdgcn_sched_barrier(0); __builtin_amdgcn_s_barrier(); } while (0)
#define MFMAQ(qm, qn, bq) do { \
  __builtin_amdgcn_s_setprio(1); \
  _Pragma("unroll") for (int mf_ = 0; mf_ < 4; mf_++) \
  _Pragma("unroll") for (int nf_ = 0; nf_ < 2; nf_++) \
  _Pragma("unroll") for (int ks_ = 0; ks_ < 2; ks_++) \
    acc[(qm)*4+mf_][(qn)*2+nf_] = __builtin_amdgcn_mfma_f32_16x16x32_bf16( \
        af[mf_][ks_], bq[nf_][ks_], acc[(qm)*4+mf_][(qn)*2+nf_], 0, 0, 0); \
  __builtin_amdgcn_s_setprio(0); } while (0)

template<int EPI>
__global__ __launch_bounds__(512, 2) void gemm256(
    const u16* __restrict__ A, const u16* __restrict__ Bt,
    void* __restrict__ Cv, const float* __restrict__ resid,
    const u16* __restrict__ gate, int M, int N, int K) {
  extern __shared__ u16 lds[];              // [2 bufs][A 16384 u16 | B 16384 u16]
  int nwg = gridDim.x, bid = (int)blockIdx.x;
  int cpx = nwg >> 3;
  int swz = (bid & 7) * cpx + (bid >> 3);   // XCD-contiguous chunks (T1); all grids %8==0
  int mt = M >> 8;
  int m0 = (swz % mt) << 8;
  int n0 = (swz / mt) << 8;
  int tid = threadIdx.x, lane = tid & 63, wave = tid >> 6;
  int wm = wave >> 2, wn = wave & 3;

  f32x4 acc[8][4];
  f32x4 zero = {0.f, 0.f, 0.f, 0.f};
  #pragma unroll
  for (int i = 0; i < 8; i++)
    #pragma unroll
    for (int j = 0; j < 4; j++) acc[i][j] = zero;

  // staging: per op per K-tile = 4 x global_load_lds/thread; LDS linear, global pre-swizzled
  int sgrow = lane >> 3;
  int sgcol = ((lane & 7) ^ (lane >> 3)) << 3;               // u16 col = logical chunk * 8
  const u16* gA = A  + (size_t)(m0 + wave*8 + sgrow) * K + sgcol;
  const u16* gB = Bt + (size_t)(n0 + wave*8 + sgrow) * K + sgcol;
  size_t K64 = (size_t)64 * K, K128 = (size_t)128 * K, K192 = (size_t)192 * K;

  // fragment reads: row r => swizzle chunk ^= (r&7) == (lane&15)&7
  int rA = lane & 15;
  int sw = rA & 7;
  int acol0 = (((lane >> 4)    ) ^ sw) << 3;                 // ks=0
  int acol1 = (((lane >> 4) + 4) ^ sw) << 3;                 // ks=1

  bf16x8 af[4][2], b0[2][2], b1[2][2];

  auto stageA = [&](int kb, int k0) {
    u16* d = lds + kb*32768 + wave*512;
    const u16* s = gA + k0;
    async16(d,         s);
    async16(d + 4096,  s + K64);
    async16(d + 8192,  s + K128);
    async16(d + 12288, s + K192);
  };
  auto stageB = [&](int kb, int k0) {
    u16* d = lds + kb*32768 + 16384 + wave*512;
    const u16* s = gB + k0;
    async16(d,         s);
    async16(d + 4096,  s + K64);
    async16(d + 8192,  s + K128);
    async16(d + 12288, s + K192);
  };
  auto loadA = [&](int kb, int qm) {
    const u16* base = lds + kb*32768 + (wm*128 + qm*64 + rA)*64;
    #pragma unroll
    for (int mf = 0; mf < 4; mf++) {
      af[mf][0] = *(const bf16x8*)(base + mf*1024 + acol0);
      af[mf][1] = *(const bf16x8*)(base + mf*1024 + acol1);
    }
  };
  auto loadB = [&](int kb, int qn, bf16x8 (&bq)[2][2]) {
    const u16* base = lds + kb*32768 + 16384 + (wn*64 + qn*32 + rA)*64;
    #pragma unroll
    for (int nf = 0; nf < 2; nf++) {
      bq[nf][0] = *(const bf16x8*)(base + nf*1024 + acol0);
      bq[nf][1] = *(const bf16x8*)(base + nf*1024 + acol1);
    }
  };

  int nt = K >> 6;
  // prologue: stage K-tiles 0 and 1, land tile 0 (vmcnt(8) leaves tile 1 in flight)
  stageA(0, 0); stageB(0, 0);
  if (nt > 1) { stageA(1, 64); stageB(1, 64); }
  __builtin_amdgcn_sched_barrier(0);
  if (nt > 1) asm volatile("s_waitcnt vmcnt(8)" ::: "memory");
  else        asm volatile("s_waitcnt vmcnt(0)" ::: "memory");
  __builtin_amdgcn_sched_barrier(0);
  __builtin_amdgcn_s_barrier();

  for (int k = 0; k < nt; k++) {
    int kb = k & 1;
    bool pre = (k + 2) < nt;
    int k2 = (k + 2) << 6;
    // phase 0: quadrant (0,0)
    loadA(kb, 0); loadB(kb, 0, b0);
    MIDBAR(); MFMAQ(0, 0, b0); ENDBAR();
    // phase 1: quadrant (0,1)
    loadB(kb, 1, b1);
    MIDBAR(); MFMAQ(0, 1, b1); ENDBAR();
    // phase 2: quadrant (1,0); prefetch B of k+2 (B regions consumed end-ph1)
    loadA(kb, 1);
    if (pre) stageB(kb, k2);
    MIDBAR(); MFMAQ(1, 0, b0); ENDBAR();
    // phase 3: quadrant (1,1); prefetch A of k+2 (A regions consumed end-ph2)
    if (pre) stageA(kb, k2);
    MIDBAR(); MFMAQ(1, 1, b1);
    __builtin_amdgcn_sched_barrier(0);
    if (pre) asm volatile("s_waitcnt vmcnt(8)" ::: "memory");   // 8 newest = k+2 prefetch
    else     asm volatile("s_waitcnt vmcnt(0)" ::: "memory");   // epilogue drain
    __builtin_amdgcn_sched_barrier(0);
    __builtin_amdgcn_s_barrier();
  }

  // C/D layout: col = lane&15, row = (lane>>4)*4 + j
  #pragma unroll
  for (int mf = 0; mf < 8; mf++)
    #pragma unroll
    for (int nf = 0; nf < 4; nf++)
      #pragma unroll
      for (int j = 0; j < 4; j++) {
        int rr = m0 + wm*128 + mf*16 + (lane >> 4)*4 + j;
        int cc = n0 + wn*64 + nf*16 + (lane & 15);
        size_t idx = (size_t)rr * N + cc;
        float v = acc[mf][nf][j];
        if constexpr (EPI == 0) {
          ((u16*)Cv)[idx] = f2bf(v);
        } else if constexpr (EPI == 1) {
          ((float*)Cv)[idx] = v + resid[idx];
        } else {
          float g = bf2f(gate[idx]);
          float sg = g / (1.f + __expf(-g));
          ((u16*)Cv)[idx] = f2bf(sg * v);
        }
      }
}

// ---------------- Flash attention, causal, GQA 4:1 ----------------
__global__ __launch_bounds__(256, 2) void attn_kernel(
    const u16* __restrict__ q, const u16* __restrict__ k,
    const u16* __restrict__ vt, u16* __restrict__ out) {
  __shared__ u16 Ks[64*128];
  __shared__ u16 Vs[128*64];
  __shared__ u16 Ps[4*16*64];
  int bid = blockIdx.x;
  int qt = bid & 15;
  int h  = (bid >> 4) & 31;
  int b  = bid >> 9;
  int kvh = h >> 2;
  int tid = threadIdx.x, lane = tid & 63, wave = tid >> 6;
  int q0 = qt << 6;

  bf16x8 qf[4];
  {
    const u16* qb_ = q + (size_t)(b*1024 + q0 + wave*16 + (lane & 15))*4096 + h*128 + (lane >> 4)*8;
    #pragma unroll
    for (int ks = 0; ks < 4; ks++) qf[ks] = *(const bf16x8*)(qb_ + ks*32);
  }
  f32x4 o[8];
  f32x4 zero = {0.f,0.f,0.f,0.f};
  #pragma unroll
  for (int i = 0; i < 8; i++) o[i] = zero;
  float m[4] = {-1e30f,-1e30f,-1e30f,-1e30f};
  float l[4] = {0.f,0.f,0.f,0.f};

  int kr[4], kc[4], vr[4], vc[4];
  #pragma unroll
  for (int i = 0; i < 4; i++) {
    int c = i*256 + tid;
    kr[i] = c >> 4; kc[i] = ((c & 15)*16) ^ ((kr[i] & 7) << 4);
    vr[i] = c >> 3; vc[i] = ((c & 7)*16)  ^ ((vr[i] & 7) << 4);
  }

  for (int t = 0; t <= qt; t++) {
    int kv0 = t << 6;
    #pragma unroll
    for (int i = 0; i < 4; i++) {
      async16(Ks + i*2048 + wave*512, k  + (size_t)(b*1024 + kv0 + kr[i])*1024 + kvh*128 + (kc[i] >> 1));
      async16(Vs + i*2048 + wave*512, vt + (size_t)((b*8 + kvh)*128 + vr[i])*1024 + kv0 + (vc[i] >> 1));
    }
    __syncthreads();

    f32x4 s[4];
    #pragma unroll
    for (int nf = 0; nf < 4; nf++) {
      s[nf] = zero;
      #pragma unroll
      for (int ks = 0; ks < 4; ks++) {
        int r = nf*16 + (lane & 15);
        int c2 = (ks*32 + (lane >> 4)*8)*2;
        bf16x8 kf = *(const bf16x8*)(Ks + r*128 + ((c2 ^ ((r & 7) << 4)) >> 1));
        s[nf] = __builtin_amdgcn_mfma_f32_16x16x32_bf16(qf[ks], kf, s[nf], 0, 0, 0);
      }
    }
    if (t == qt) {
      #pragma unroll
      for (int nf = 0; nf < 4; nf++)
        #pragma unroll
        for (int j = 0; j < 4; j++) {
          int cc = nf*16 + (lane & 15);
          int rr = wave*16 + (lane >> 4)*4 + j;
          if (cc > rr) s[nf][j] = -1e30f;
        }
    }
    #pragma unroll
    for (int j = 0; j < 4; j++) {
      float mx = fmaxf(fmaxf(s[0][j], s[1][j]), fmaxf(s[2][j], s[3][j]));
      #pragma unroll
      for (int d = 1; d < 16; d <<= 1) mx = fmaxf(mx, __shfl_xor(mx, d, 64));
      float mn = fmaxf(m[j], mx);
      float f = __expf(m[j] - mn);
      m[j] = mn;
      float ssum = 0.f;
      #pragma unroll
      for (int nf = 0; nf < 4; nf++) {
        float p = __expf(s[nf][j] - mn);
        s[nf][j] = p; ssum += p;
      }
      #pragma unroll
      for (int d = 1; d < 16; d <<= 1) ssum += __shfl_xor(ssum, d, 64);
      l[j] = l[j]*f + ssum;
      #pragma unroll
      for (int nf = 0; nf < 8; nf++) o[nf][j] *= f;
    }
    #pragma unroll
    for (int nf = 0; nf < 4; nf++)
      #pragma unroll
      for (int j = 0; j < 4; j++) {
        int rr = (lane >> 4)*4 + j;
        int cb = ((nf*16 + (lane & 15))*2) ^ ((rr & 7) << 4);
        Ps[wave*1024 + rr*64 + (cb >> 1)] = f2bf(s[nf][j]);
      }
    #pragma unroll
    for (int ks2 = 0; ks2 < 2; ks2++) {
      int mr = lane & 15;
      int c2 = (ks2*32 + (lane >> 4)*8)*2;
      bf16x8 pa = *(const bf16x8*)(Ps + wave*1024 + mr*64 + ((c2 ^ ((mr & 7) << 4)) >> 1));
      #pragma unroll
      for (int nf = 0; nf < 8; nf++) {
        int d = nf*16 + (lane & 15);
        bf16x8 vf = *(const bf16x8*)(Vs + d*64 + ((c2 ^ ((d & 7) << 4)) >> 1));
        o[nf] = __builtin_amdgcn_mfma_f32_16x16x32_bf16(pa, vf, o[nf], 0, 0, 0);
      }
    }
    __syncthreads();
  }

  float inv[4];
  #pragma unroll
  for (int j = 0; j < 4; j++) inv[j] = 1.f / l[j];
  u16* ob = out + (size_t)(b*1024 + q0 + wave*16)*4096 + h*128;
  #pragma unroll
  for (int nf = 0; nf < 8; nf++)
    #pragma unroll
    for (int j = 0; j < 4; j++) {
      int rr = (lane >> 4)*4 + j;
      int cc = nf*16 + (lane & 15);
      ob[(size_t)rr*4096 + cc] = f2bf(o[nf][j] * inv[j]);
    }
}

// ---------------- driver ----------------
extern "C" void kernel_launch(void* const* d_in, const int* in_sizes, int n_in,
                              void* d_out, int out_size, void* d_ws, size_t ws_size,
                              hipStream_t stream) {
  (void)in_sizes; (void)n_in; (void)out_size;
  const float* hidden = (const float*)d_in[0];
  const float* Wq  = (const float*)d_in[3];
  const float* Wk  = (const float*)d_in[4];
  const float* Wv  = (const float*)d_in[5];
  const float* Wo  = (const float*)d_in[6];
  const float* ln1 = (const float*)d_in[7];
  const float* ln2 = (const float*)d_in[8];
  const float* Wg  = (const float*)d_in[9];
  const float* Wu  = (const float*)d_in[10];
  const float* Wd  = (const float*)d_in[11];
  float* out = (float*)d_out;

  char* ws = (char*)d_ws;
  size_t off = 0;
  auto alloc = [&](size_t b) { char* p = ws + off; off += (b + 4095) & ~(size_t)4095; return p; };
  u16*  W1   = (u16*)alloc(90177536);
  u16*  h1   = (u16*)alloc(33554432);
  u16*  qb   = (u16*)alloc(33554432);
  u16*  kb   = (u16*)alloc(8388608);
  u16*  vb   = (u16*)alloc(8388608);
  u16*  vtb  = (u16*)alloc(8388608);
  float* hmid = (float*)alloc(67108864);
  u16*  gb   = (u16*)alloc(90177536);
  if (off > ws_size) return;

  u16* wqT = W1;
  u16* wkT = W1 + 16777216;
  u16* wvT = wkT + 4194304;

  // allow 128 KiB dynamic LDS for the 8-phase GEMM (idempotent host-side calls)
  hipFuncSetAttribute((const void*)gemm256<0>, hipFuncAttributeMaxDynamicSharedMemorySize, 131072);
  hipFuncSetAttribute((const void*)gemm256<1>, hipFuncAttributeMaxDynamicSharedMemorySize, 131072);
  hipFuncSetAttribute((const void*)gemm256<2>, hipFuncAttributeMaxDynamicSharedMemorySize, 131072);

  dim3 blk(256);
  // 1) QKV weights -> bf16 transposed
  conv_t<<<dim3(64, 64),  blk, 0, stream>>>(Wq, wqT, 4096, 4096);
  conv_t<<<dim3(16, 64),  blk, 0, stream>>>(Wk, wkT, 4096, 1024);
  conv_t<<<dim3(16, 64),  blk, 0, stream>>>(Wv, wvT, 4096, 1024);
  // 2) norm1
  rmsnorm_kernel<<<4096, blk, 0, stream>>>(hidden, ln1, h1);
  // 3) QKV projections (Q on 256-tile; K/V too narrow -> 128-tile)
  gemm256<0><<<256, 512, 131072, stream>>>(h1, wqT, qb, nullptr, nullptr, 4096, 4096, 4096);
  gemm_bt<0><<<256, blk, 0, stream>>>(h1, wkT, kb, nullptr, nullptr, 4096, 1024, 4096);
  gemm_bt<0><<<256, blk, 0, stream>>>(h1, wvT, vb, nullptr, nullptr, 4096, 1024, 4096);
  // 4) RoPE (q also gets 1/sqrt(HD))
  rope_kernel<<<4096, blk, 0, stream>>>(qb, kb);
  // 5) V transpose
  vtrans<<<dim3(4, 32, 32), dim3(32, 8), 0, stream>>>(vb, vtb);
  // 6) attention -> h1
  attn_kernel<<<2048, blk, 0, stream>>>(qb, kb, vtb, h1);
  // 7) Wo + residual -> hmid (fp32)
  conv_t<<<dim3(64, 64), blk, 0, stream>>>(Wo, W1, 4096, 4096);
  gemm256<1><<<256, 512, 131072, stream>>>(h1, W1, hmid, hidden, nullptr, 4096, 4096, 4096);
  // 8) norm2 -> qb
  rmsnorm_kernel<<<4096, blk, 0, stream>>>(hmid, ln2, qb);
  // 9) gate
  conv_t<<<dim3(172, 64), blk, 0, stream>>>(Wg, W1, 4096, 11008);
  gemm256<0><<<688, 512, 131072, stream>>>(qb, W1, gb, nullptr, nullptr, 4096, 11008, 4096);
  // 10) up, epilogue act = silu(gate)*up (in place over gb)
  conv_t<<<dim3(172, 64), blk, 0, stream>>>(Wu, W1, 4096, 11008);
  gemm256<2><<<688, 512, 131072, stream>>>(qb, W1, gb, nullptr, gb, 4096, 11008, 4096);
  // 11) down + residual -> d_out (fp32)
  conv_t<<<dim3(64, 172), blk, 0, stream>>>(Wd, W1, 11008, 4096);
  gemm256<1><<<256, 512, 131072, stream>>>(gb, W1, out, hmid, nullptr, 4096, 4096, 11008);
}

// Round 3
// 1810.689 us; speedup vs baseline: 1.1321x; 1.0297x over previous
//
#include <hip/hip_runtime.h>

#define DEVINL __device__ __forceinline__

typedef unsigned short u16;
typedef __attribute__((ext_vector_type(8))) short bf16x8;   // 8 bf16 = 4 VGPRs (MFMA A/B frag)
typedef __attribute__((ext_vector_type(4))) float f32x4;     // MFMA C/D frag
typedef __attribute__((ext_vector_type(4))) unsigned short u16x4;

// B=4, S=1024, HID=4096, NH=32, NKV=8, HD=128, FF=11008

DEVINL float bf2f(u16 u) { union { unsigned i; float f; } x; x.i = ((unsigned)u) << 16; return x.f; }
DEVINL u16 f2bf(float f) {                       // round-to-nearest-even
  union { float f; unsigned i; } x; x.f = f;
  unsigned r = x.i + 0x7fffu + ((x.i >> 16) & 1u);
  return (u16)(r >> 16);
}

// async global->LDS, 16B per lane; lds base must be wave-uniform (HW: base + lane*16)
DEVINL void async16(u16* lds, const u16* g) {
  __builtin_amdgcn_global_load_lds((const __attribute__((address_space(1))) unsigned*)g,
                                   (__attribute__((address_space(3))) unsigned*)lds, 16, 0, 0);
}

// ---------------- weight convert + transpose: in fp32 [K,N] -> out bf16 [N,K] ----------------
__global__ __launch_bounds__(256) void conv_t(const float* __restrict__ in,
                                              u16* __restrict__ out, int K, int N) {
  __shared__ float tile[64][65];
  int k0 = blockIdx.y << 6, n0 = blockIdx.x << 6;
  int t = threadIdx.x;
  int r = t >> 4, c4 = (t & 15) << 2;
  #pragma unroll
  for (int it = 0; it < 4; it++) {
    int row = r + it*16;
    f32x4 v = *(const f32x4*)(in + (size_t)(k0 + row)*N + n0 + c4);
    tile[row][c4+0] = v[0]; tile[row][c4+1] = v[1];
    tile[row][c4+2] = v[2]; tile[row][c4+3] = v[3];
  }
  __syncthreads();
  #pragma unroll
  for (int it = 0; it < 4; it++) {
    int nrow = r + it*16;
    u16x4 ov;
    #pragma unroll
    for (int e = 0; e < 4; e++) ov[e] = f2bf(tile[c4+e][nrow]);
    *(u16x4*)(out + (size_t)(n0 + nrow)*K + k0 + c4) = ov;
  }
}

// ---------------- RMSNorm: fp32 in [4096 rows x 4096] -> bf16 out ----------------
__global__ __launch_bounds__(256) void rmsnorm_kernel(const float* __restrict__ x,
                                                      const float* __restrict__ w,
                                                      u16* __restrict__ out) {
  int row = blockIdx.x, t = threadIdx.x;
  const float* xr = x + (size_t)row * 4096;
  f32x4 v[4];
  float ss = 0.f;
  #pragma unroll
  for (int i = 0; i < 4; i++) {
    v[i] = *(const f32x4*)(xr + (t + 256*i)*4);
    ss += v[i][0]*v[i][0] + v[i][1]*v[i][1] + v[i][2]*v[i][2] + v[i][3]*v[i][3];
  }
  #pragma unroll
  for (int d = 1; d < 64; d <<= 1) ss += __shfl_xor(ss, d, 64);
  __shared__ float ps[4];
  if ((t & 63) == 0) ps[t >> 6] = ss;
  __syncthreads();
  float scale = rsqrtf((ps[0]+ps[1]+ps[2]+ps[3]) * (1.f/4096.f) + 1e-6f);
  #pragma unroll
  for (int i = 0; i < 4; i++) {
    f32x4 wv = *(const f32x4*)(w + (t + 256*i)*4);
    u16x4 o;
    #pragma unroll
    for (int e = 0; e < 4; e++) o[e] = f2bf(v[i][e] * scale * wv[e]);
    *(u16x4*)(out + (size_t)row*4096 + (t + 256*i)*4) = o;
  }
}

// ---------------- RoPE in-place on q [tok,32*128] & k [tok,8*128]; q gets 1/sqrt(HD) ----------------
__global__ __launch_bounds__(256) void rope_kernel(u16* __restrict__ q, u16* __restrict__ k) {
  int tok = blockIdx.x;            // b*1024 + s ; position id == s
  int s = tok & 1023;
  __shared__ float cs[64], sn[64];
  int t = threadIdx.x;
  if (t < 64) {
    float inv = __expf(-(float)t * 0.14391156934f);  // ln(10000)/64
    float ang = (float)s * inv;
    cs[t] = cosf(ang); sn[t] = sinf(ang);
  }
  __syncthreads();
  const float qscale = 0.08838834764831845f;          // 1/sqrt(128)
  size_t qbase = (size_t)tok * 4096;
  #pragma unroll
  for (int it = 0; it < 8; it++) {
    int item = t + it*256; int h = item >> 6, j = item & 63;
    size_t i0 = qbase + h*128 + j;
    float x1 = bf2f(q[i0]), x2 = bf2f(q[i0+64]);
    float c = cs[j], si = sn[j];
    q[i0]    = f2bf((x1*c - x2*si) * qscale);
    q[i0+64] = f2bf((x2*c + x1*si) * qscale);
  }
  size_t kbase = (size_t)tok * 1024;
  #pragma unroll
  for (int it = 0; it < 2; it++) {
    int item = t + it*256; int h = item >> 6, j = item & 63;
    size_t i0 = kbase + h*128 + j;
    float x1 = bf2f(k[i0]), x2 = bf2f(k[i0+64]);
    float c = cs[j], si = sn[j];
    k[i0]    = f2bf(x1*c - x2*si);
    k[i0+64] = f2bf(x2*c + x1*si);
  }
}

// ---------------- V transpose per (b,kvh): [1024 x 128] -> vt [128 x 1024] ----------------
__global__ __launch_bounds__(256) void vtrans(const u16* __restrict__ v, u16* __restrict__ vt) {
  __shared__ u16 tile[32][33];
  int bh = blockIdx.z; int b = bh >> 3, kvh = bh & 7;
  int d0 = blockIdx.x << 5, s0 = blockIdx.y << 5;
  int tx = threadIdx.x, ty = threadIdx.y;   // (32,8)
  for (int r = ty; r < 32; r += 8)
    tile[r][tx] = v[(size_t)(b*1024 + s0 + r)*1024 + kvh*128 + d0 + tx];
  __syncthreads();
  for (int r = ty; r < 32; r += 8)
    vt[(size_t)((b*8 + kvh)*128 + d0 + r)*1024 + s0 + tx] = tile[tx][r];
}

// ---------------- 128-tile GEMM (kept for K/V projections: N=1024 too small for 256-tiles) ----------------
template<int EPI>
__global__ __launch_bounds__(256, 2) void gemm_bt(
    const u16* __restrict__ A, const u16* __restrict__ Bt,
    void* __restrict__ Cv, const float* __restrict__ resid,
    const u16* __restrict__ gate, int M, int N, int K) {
  __shared__ u16 As[128*64];
  __shared__ u16 Bs[128*64];
  int nwg = gridDim.x;
  int bid = (int)blockIdx.x;
  int cpx = nwg >> 3;
  int swz = (bid & 7) * cpx + (bid >> 3);
  int mt = M >> 7;
  int m0 = (swz % mt) << 7;
  int n0 = (swz / mt) << 7;
  int tid = threadIdx.x;
  int lane = tid & 63, wave = tid >> 6;
  int wm = wave >> 1, wn = wave & 1;

  f32x4 acc[4][4];
  f32x4 zero = {0.f, 0.f, 0.f, 0.f};
  #pragma unroll
  for (int i = 0; i < 4; i++)
    #pragma unroll
    for (int j = 0; j < 4; j++) acc[i][j] = zero;

  int arow[4], acolb[4];
  #pragma unroll
  for (int i = 0; i < 4; i++) {
    int c = i*256 + tid;
    arow[i]  = c >> 3;
    acolb[i] = ((c & 7) * 16) ^ ((arow[i] & 7) << 4);
  }

  int nsteps = K >> 6;
  for (int t = 0; t < nsteps; t++) {
    int k0 = t << 6;
    #pragma unroll
    for (int i = 0; i < 4; i++) {
      async16(As + i*2048 + wave*512, A  + (size_t)(m0 + arow[i])*K + k0 + (acolb[i] >> 1));
      async16(Bs + i*2048 + wave*512, Bt + (size_t)(n0 + arow[i])*K + k0 + (acolb[i] >> 1));
    }
    __syncthreads();
    #pragma unroll
    for (int ks = 0; ks < 2; ks++) {
      bf16x8 af[4], bfr[4];
      int c2 = (ks*32 + (lane >> 4)*8) * 2;
      #pragma unroll
      for (int mf = 0; mf < 4; mf++) {
        int r = wm*64 + mf*16 + (lane & 15);
        af[mf] = *(const bf16x8*)(As + r*64 + ((c2 ^ ((r & 7) << 4)) >> 1));
      }
      #pragma unroll
      for (int nf = 0; nf < 4; nf++) {
        int r = wn*64 + nf*16 + (lane & 15);
        bfr[nf] = *(const bf16x8*)(Bs + r*64 + ((c2 ^ ((r & 7) << 4)) >> 1));
      }
      #pragma unroll
      for (int mf = 0; mf < 4; mf++)
        #pragma unroll
        for (int nf = 0; nf < 4; nf++)
          acc[mf][nf] = __builtin_amdgcn_mfma_f32_16x16x32_bf16(af[mf], bfr[nf], acc[mf][nf], 0, 0, 0);
    }
    __syncthreads();
  }

  #pragma unroll
  for (int mf = 0; mf < 4; mf++)
    #pragma unroll
    for (int nf = 0; nf < 4; nf++)
      #pragma unroll
      for (int j = 0; j < 4; j++) {
        int rr = m0 + wm*64 + mf*16 + (lane >> 4)*4 + j;
        int cc = n0 + wn*64 + nf*16 + (lane & 15);
        size_t idx = (size_t)rr * N + cc;
        float v = acc[mf][nf][j];
        if constexpr (EPI == 0) {
          ((u16*)Cv)[idx] = f2bf(v);
        } else if constexpr (EPI == 1) {
          ((float*)Cv)[idx] = v + resid[idx];
        } else {
          float g = bf2f(gate[idx]);
          float sg = g / (1.f + __expf(-g));
          ((u16*)Cv)[idx] = f2bf(sg * v);
        }
      }
}

// ---------------- 256x256 GEMM, 2-barrier/K-tile with DS/MFMA overlap ----------------
// 512 thr = 8 waves (2M x 4N), wave out 128x64. BK=64, LDS 128 KiB = 2buf x (A 32KB | B 32KB).
// Per K-tile: issue afA+b0+b1 reads -> MFMA Q00,Q01 (compiler emits COUNTED lgkm waits, later
// reads stay in flight); issue afB reads into af regs (WAR handled by compiler, DS flight hides
// under Q00/Q01); lgkmcnt(0)+barrier (all waves' reads retired -> buf[kb] safe to overwrite);
// issue k+2 stage (8 G-loads overlap Q10/Q11); MFMA Q10,Q11; counted vmcnt(8) (tile k+1 landed,
// k+2's 8 loads stay in flight); barrier. Only 2 barriers/K-tile; DS bursts overlap MFMA.
#define SB0() __builtin_amdgcn_sched_barrier(0)
#define MFMAQ2(qm, qn, afr, bq) do { \
  _Pragma("unroll") for (int mf_ = 0; mf_ < 4; mf_++) \
  _Pragma("unroll") for (int nf_ = 0; nf_ < 2; nf_++) \
  _Pragma("unroll") for (int ks_ = 0; ks_ < 2; ks_++) \
    acc[(qm)*4+mf_][(qn)*2+nf_] = __builtin_amdgcn_mfma_f32_16x16x32_bf16( \
        afr[mf_][ks_], bq[nf_][ks_], acc[(qm)*4+mf_][(qn)*2+nf_], 0, 0, 0); \
} while (0)

template<int EPI>
__global__ __launch_bounds__(512, 2) void gemm256(
    const u16* __restrict__ A, const u16* __restrict__ Bt,
    void* __restrict__ Cv, const float* __restrict__ resid,
    const u16* __restrict__ gate, int M, int N, int K) {
  extern __shared__ u16 lds[];              // [2 bufs][A 16384 u16 | B 16384 u16]
  int nwg = gridDim.x, bid = (int)blockIdx.x;
  int cpx = nwg >> 3;
  int swz = (bid & 7) * cpx + (bid >> 3);   // XCD-contiguous chunks (T1); all grids %8==0
  int mt = M >> 8;
  int m0 = (swz % mt) << 8;
  int n0 = (swz / mt) << 8;
  int tid = threadIdx.x, lane = tid & 63, wave = tid >> 6;
  int wm = wave >> 2, wn = wave & 3;

  f32x4 acc[8][4];
  f32x4 zero = {0.f, 0.f, 0.f, 0.f};
  #pragma unroll
  for (int i = 0; i < 8; i++)
    #pragma unroll
    for (int j = 0; j < 4; j++) acc[i][j] = zero;

  // staging: 4 G-loads per op per K-tile per thread; LDS linear, global pre-swizzled (rule #21)
  int sgrow = lane >> 3;
  int sgcol = ((lane & 7) ^ (lane >> 3)) << 3;               // u16 col = swizzled chunk * 8
  const u16* gA = A  + (size_t)(m0 + wave*8 + sgrow) * K + sgcol;
  const u16* gB = Bt + (size_t)(n0 + wave*8 + sgrow) * K + sgcol;
  size_t K64 = (size_t)64 * K, K128 = (size_t)128 * K, K192 = (size_t)192 * K;

  // fragment reads: row r => chunk ^= (r&7)
  int rA = lane & 15;
  int sw = rA & 7;
  int acol0 = (((lane >> 4)    ) ^ sw) << 3;                 // ks=0 (u16 units)
  int acol1 = (((lane >> 4) + 4) ^ sw) << 3;                 // ks=1

  bf16x8 af[4][2], b0[2][2], b1[2][2];

  auto stageA = [&](int kb, int k0) {
    u16* d = lds + kb*32768 + wave*512;
    const u16* s = gA + k0;
    async16(d,         s);
    async16(d + 4096,  s + K64);
    async16(d + 8192,  s + K128);
    async16(d + 12288, s + K192);
  };
  auto stageB = [&](int kb, int k0) {
    u16* d = lds + kb*32768 + 16384 + wave*512;
    const u16* s = gB + k0;
    async16(d,         s);
    async16(d + 4096,  s + K64);
    async16(d + 8192,  s + K128);
    async16(d + 12288, s + K192);
  };
  auto loadA = [&](int kb, int qm) {
    const u16* base = lds + kb*32768 + (wm*128 + qm*64 + rA)*64;
    #pragma unroll
    for (int mf = 0; mf < 4; mf++) {
      af[mf][0] = *(const bf16x8*)(base + mf*1024 + acol0);
      af[mf][1] = *(const bf16x8*)(base + mf*1024 + acol1);
    }
  };
  auto loadB = [&](int kb, int qn, bf16x8 (&bq)[2][2]) {
    const u16* base = lds + kb*32768 + 16384 + (wn*64 + qn*32 + rA)*64;
    #pragma unroll
    for (int nf = 0; nf < 2; nf++) {
      bq[nf][0] = *(const bf16x8*)(base + nf*1024 + acol0);
      bq[nf][1] = *(const bf16x8*)(base + nf*1024 + acol1);
    }
  };

  int nt = K >> 6;
  // prologue: stage K-tiles 0 and 1; land tile 0 (vmcnt(8) leaves tile 1 in flight)
  stageA(0, 0); stageB(0, 0);
  if (nt > 1) { stageA(1, 64); stageB(1, 64); }
  SB0();
  if (nt > 1) asm volatile("s_waitcnt vmcnt(8)" ::: "memory");
  else        asm volatile("s_waitcnt vmcnt(0)" ::: "memory");
  SB0();
  __builtin_amdgcn_s_barrier();

  for (int k = 0; k < nt; k++) {
    int kb = k & 1;
    bool pre = (k + 2) < nt;
    int k2 = (k + 2) << 6;
    // issue A-half0 + both B halves (16 reads); counted waits let later reads fly under MFMA
    loadA(kb, 0); loadB(kb, 0, b0); loadB(kb, 1, b1);
    SB0();
    __builtin_amdgcn_s_setprio(1);
    MFMAQ2(0, 0, af, b0);
    MFMAQ2(0, 1, af, b1);
    __builtin_amdgcn_s_setprio(0);
    // A-half1 into same regs (WAR vs Q00/Q01 handled by compiler); flight hides under MFMA above
    loadA(kb, 1);
    SB0();
    asm volatile("s_waitcnt lgkmcnt(0)" ::: "memory");  // all reads of buf[kb] retired
    SB0();
    __builtin_amdgcn_s_barrier();                        // cross-wave: buf[kb] free to overwrite
    if (pre) { stageB(kb, k2); stageA(kb, k2); }         // 8 G-loads overlap Q10/Q11
    SB0();
    __builtin_amdgcn_s_setprio(1);
    MFMAQ2(1, 0, af, b0);
    MFMAQ2(1, 1, af, b1);
    __builtin_amdgcn_s_setprio(0);
    SB0();
    if (pre) asm volatile("s_waitcnt vmcnt(8)" ::: "memory");  // 8 newest = k+2; k+1 landed
    else     asm volatile("s_waitcnt vmcnt(0)" ::: "memory");  // epilogue drain
    SB0();
    __builtin_amdgcn_s_barrier();                        // tile k+1 visible to all waves
  }

  // C/D layout: col = lane&15, row = (lane>>4)*4 + j
  #pragma unroll
  for (int mf = 0; mf < 8; mf++)
    #pragma unroll
    for (int nf = 0; nf < 4; nf++)
      #pragma unroll
      for (int j = 0; j < 4; j++) {
        int rr = m0 + wm*128 + mf*16 + (lane >> 4)*4 + j;
        int cc = n0 + wn*64 + nf*16 + (lane & 15);
        size_t idx = (size_t)rr * N + cc;
        float v = acc[mf][nf][j];
        if constexpr (EPI == 0) {
          ((u16*)Cv)[idx] = f2bf(v);
        } else if constexpr (EPI == 1) {
          ((float*)Cv)[idx] = v + resid[idx];
        } else {
          float g = bf2f(gate[idx]);
          float sg = g / (1.f + __expf(-g));
          ((u16*)Cv)[idx] = f2bf(sg * v);
        }
      }
}

// ---------------- Flash attention, causal, GQA 4:1 ----------------
__global__ __launch_bounds__(256, 2) void attn_kernel(
    const u16* __restrict__ q, const u16* __restrict__ k,
    const u16* __restrict__ vt, u16* __restrict__ out) {
  __shared__ u16 Ks[64*128];
  __shared__ u16 Vs[128*64];
  __shared__ u16 Ps[4*16*64];
  int bid = blockIdx.x;
  int qt = bid & 15;
  int h  = (bid >> 4) & 31;
  int b  = bid >> 9;
  int kvh = h >> 2;
  int tid = threadIdx.x, lane = tid & 63, wave = tid >> 6;
  int q0 = qt << 6;

  bf16x8 qf[4];
  {
    const u16* qb_ = q + (size_t)(b*1024 + q0 + wave*16 + (lane & 15))*4096 + h*128 + (lane >> 4)*8;
    #pragma unroll
    for (int ks = 0; ks < 4; ks++) qf[ks] = *(const bf16x8*)(qb_ + ks*32);
  }
  f32x4 o[8];
  f32x4 zero = {0.f,0.f,0.f,0.f};
  #pragma unroll
  for (int i = 0; i < 8; i++) o[i] = zero;
  float m[4] = {-1e30f,-1e30f,-1e30f,-1e30f};
  float l[4] = {0.f,0.f,0.f,0.f};

  int kr[4], kc[4], vr[4], vc[4];
  #pragma unroll
  for (int i = 0; i < 4; i++) {
    int c = i*256 + tid;
    kr[i] = c >> 4; kc[i] = ((c & 15)*16) ^ ((kr[i] & 7) << 4);
    vr[i] = c >> 3; vc[i] = ((c & 7)*16)  ^ ((vr[i] & 7) << 4);
  }

  for (int t = 0; t <= qt; t++) {
    int kv0 = t << 6;
    #pragma unroll
    for (int i = 0; i < 4; i++) {
      async16(Ks + i*2048 + wave*512, k  + (size_t)(b*1024 + kv0 + kr[i])*1024 + kvh*128 + (kc[i] >> 1));
      async16(Vs + i*2048 + wave*512, vt + (size_t)((b*8 + kvh)*128 + vr[i])*1024 + kv0 + (vc[i] >> 1));
    }
    __syncthreads();

    f32x4 s[4];
    #pragma unroll
    for (int nf = 0; nf < 4; nf++) {
      s[nf] = zero;
      #pragma unroll
      for (int ks = 0; ks < 4; ks++) {
        int r = nf*16 + (lane & 15);
        int c2 = (ks*32 + (lane >> 4)*8)*2;
        bf16x8 kf = *(const bf16x8*)(Ks + r*128 + ((c2 ^ ((r & 7) << 4)) >> 1));
        s[nf] = __builtin_amdgcn_mfma_f32_16x16x32_bf16(qf[ks], kf, s[nf], 0, 0, 0);
      }
    }
    if (t == qt) {
      #pragma unroll
      for (int nf = 0; nf < 4; nf++)
        #pragma unroll
        for (int j = 0; j < 4; j++) {
          int cc = nf*16 + (lane & 15);
          int rr = wave*16 + (lane >> 4)*4 + j;
          if (cc > rr) s[nf][j] = -1e30f;
        }
    }
    #pragma unroll
    for (int j = 0; j < 4; j++) {
      float mx = fmaxf(fmaxf(s[0][j], s[1][j]), fmaxf(s[2][j], s[3][j]));
      #pragma unroll
      for (int d = 1; d < 16; d <<= 1) mx = fmaxf(mx, __shfl_xor(mx, d, 64));
      float mn = fmaxf(m[j], mx);
      float f = __expf(m[j] - mn);
      m[j] = mn;
      float ssum = 0.f;
      #pragma unroll
      for (int nf = 0; nf < 4; nf++) {
        float p = __expf(s[nf][j] - mn);
        s[nf][j] = p; ssum += p;
      }
      #pragma unroll
      for (int d = 1; d < 16; d <<= 1) ssum += __shfl_xor(ssum, d, 64);
      l[j] = l[j]*f + ssum;
      #pragma unroll
      for (int nf = 0; nf < 8; nf++) o[nf][j] *= f;
    }
    #pragma unroll
    for (int nf = 0; nf < 4; nf++)
      #pragma unroll
      for (int j = 0; j < 4; j++) {
        int rr = (lane >> 4)*4 + j;
        int cb = ((nf*16 + (lane & 15))*2) ^ ((rr & 7) << 4);
        Ps[wave*1024 + rr*64 + (cb >> 1)] = f2bf(s[nf][j]);
      }
    #pragma unroll
    for (int ks2 = 0; ks2 < 2; ks2++) {
      int mr = lane & 15;
      int c2 = (ks2*32 + (lane >> 4)*8)*2;
      bf16x8 pa = *(const bf16x8*)(Ps + wave*1024 + mr*64 + ((c2 ^ ((mr & 7) << 4)) >> 1));
      #pragma unroll
      for (int nf = 0; nf < 8; nf++) {
        int d = nf*16 + (lane & 15);
        bf16x8 vf = *(const bf16x8*)(Vs + d*64 + ((c2 ^ ((d & 7) << 4)) >> 1));
        o[nf] = __builtin_amdgcn_mfma_f32_16x16x32_bf16(pa, vf, o[nf], 0, 0, 0);
      }
    }
    __syncthreads();
  }

  float inv[4];
  #pragma unroll
  for (int j = 0; j < 4; j++) inv[j] = 1.f / l[j];
  u16* ob = out + (size_t)(b*1024 + q0 + wave*16)*4096 + h*128;
  #pragma unroll
  for (int nf = 0; nf < 8; nf++)
    #pragma unroll
    for (int j = 0; j < 4; j++) {
      int rr = (lane >> 4)*4 + j;
      int cc = nf*16 + (lane & 15);
      ob[(size_t)rr*4096 + cc] = f2bf(o[nf][j] * inv[j]);
    }
}

// ---------------- driver ----------------
extern "C" void kernel_launch(void* const* d_in, const int* in_sizes, int n_in,
                              void* d_out, int out_size, void* d_ws, size_t ws_size,
                              hipStream_t stream) {
  (void)in_sizes; (void)n_in; (void)out_size;
  const float* hidden = (const float*)d_in[0];
  const float* Wq  = (const float*)d_in[3];
  const float* Wk  = (const float*)d_in[4];
  const float* Wv  = (const float*)d_in[5];
  const float* Wo  = (const float*)d_in[6];
  const float* ln1 = (const float*)d_in[7];
  const float* ln2 = (const float*)d_in[8];
  const float* Wg  = (const float*)d_in[9];
  const float* Wu  = (const float*)d_in[10];
  const float* Wd  = (const float*)d_in[11];
  float* out = (float*)d_out;

  char* ws = (char*)d_ws;
  size_t off = 0;
  auto alloc = [&](size_t b) { char* p = ws + off; off += (b + 4095) & ~(size_t)4095; return p; };
  u16*  W1   = (u16*)alloc(90177536);
  u16*  h1   = (u16*)alloc(33554432);
  u16*  qb   = (u16*)alloc(33554432);
  u16*  kb   = (u16*)alloc(8388608);
  u16*  vb   = (u16*)alloc(8388608);
  u16*  vtb  = (u16*)alloc(8388608);
  float* hmid = (float*)alloc(67108864);
  u16*  gb   = (u16*)alloc(90177536);
  if (off > ws_size) return;

  u16* wqT = W1;
  u16* wkT = W1 + 16777216;
  u16* wvT = wkT + 4194304;

  hipFuncSetAttribute((const void*)gemm256<0>, hipFuncAttributeMaxDynamicSharedMemorySize, 131072);
  hipFuncSetAttribute((const void*)gemm256<1>, hipFuncAttributeMaxDynamicSharedMemorySize, 131072);
  hipFuncSetAttribute((const void*)gemm256<2>, hipFuncAttributeMaxDynamicSharedMemorySize, 131072);

  dim3 blk(256);
  // 1) QKV weights -> bf16 transposed
  conv_t<<<dim3(64, 64),  blk, 0, stream>>>(Wq, wqT, 4096, 4096);
  conv_t<<<dim3(16, 64),  blk, 0, stream>>>(Wk, wkT, 4096, 1024);
  conv_t<<<dim3(16, 64),  blk, 0, stream>>>(Wv, wvT, 4096, 1024);
  // 2) norm1
  rmsnorm_kernel<<<4096, blk, 0, stream>>>(hidden, ln1, h1);
  // 3) QKV projections (Q on 256-tile; K/V too narrow -> 128-tile)
  gemm256<0><<<256, 512, 131072, stream>>>(h1, wqT, qb, nullptr, nullptr, 4096, 4096, 4096);
  gemm_bt<0><<<256, blk, 0, stream>>>(h1, wkT, kb, nullptr, nullptr, 4096, 1024, 4096);
  gemm_bt<0><<<256, blk, 0, stream>>>(h1, wvT, vb, nullptr, nullptr, 4096, 1024, 4096);
  // 4) RoPE (q also gets 1/sqrt(HD))
  rope_kernel<<<4096, blk, 0, stream>>>(qb, kb);
  // 5) V transpose
  vtrans<<<dim3(4, 32, 32), dim3(32, 8), 0, stream>>>(vb, vtb);
  // 6) attention -> h1
  attn_kernel<<<2048, blk, 0, stream>>>(qb, kb, vtb, h1);
  // 7) Wo + residual -> hmid (fp32)
  conv_t<<<dim3(64, 64), blk, 0, stream>>>(Wo, W1, 4096, 4096);
  gemm256<1><<<256, 512, 131072, stream>>>(h1, W1, hmid, hidden, nullptr, 4096, 4096, 4096);
  // 8) norm2 -> qb
  rmsnorm_kernel<<<4096, blk, 0, stream>>>(hmid, ln2, qb);
  // 9) gate
  conv_t<<<dim3(172, 64), blk, 0, stream>>>(Wg, W1, 4096, 11008);
  gemm256<0><<<688, 512, 131072, stream>>>(qb, W1, gb, nullptr, nullptr, 4096, 11008, 4096);
  // 10) up, epilogue act = silu(gate)*up (in place over gb)
  conv_t<<<dim3(172, 64), blk, 0, stream>>>(Wu, W1, 4096, 11008);
  gemm256<2><<<688, 512, 131072, stream>>>(qb, W1, gb, nullptr, gb, 4096, 11008, 4096);
  // 11) down + residual -> d_out (fp32)
  conv_t<<<dim3(64, 172), blk, 0, stream>>>(Wd, W1, 11008, 4096);
  gemm256<1><<<256, 512, 131072, stream>>>(gb, W1, out, hmid, nullptr, 4096, 4096, 11008);
}